// Round 4
// baseline (674.891 us; speedup 1.0000x reference)
//
#include <hip/hip_runtime.h>
#include <hip/hip_bf16.h>
#include <stdint.h>

// Qwen3.5 MoE block: router top-2 sparse dispatch + shared expert (SwiGLU), bf16 MFMA.
// B=2,S=1024 -> TOK=2048 tokens. H=2048, I=1408, IS=5632, E=8, K=2. Output f32.
// Round 4: global_load_lds(16B) staging, bijective XCD swizzle (mt-fastest for
// weight-panel L2 reuse), split-K=2 shared-down, d_out as pure atomic accumulator.
#define TOK   2048
#define HDIM  2048
#define IDIM  1408
#define ISDIM 5632
#define NEXP  8

typedef float  f32x4  __attribute__((ext_vector_type(4)));
typedef short  bf16x8 __attribute__((ext_vector_type(8)));

__device__ __forceinline__ unsigned short f2b(float f) {
  union { float f; uint32_t u; } v; v.f = f;
  return (unsigned short)((v.u + 0x7fffu + ((v.u >> 16) & 1u)) >> 16); // RNE
}

// async global->LDS DMA, 16 B per lane. LDS dest must be wave-uniform base
// (HW writes base + lane*16); global src is per-lane.
__device__ __forceinline__ void async16(void* lds, const void* g) {
  __builtin_amdgcn_global_load_lds(
      (const __attribute__((address_space(1))) unsigned int*)g,
      (__attribute__((address_space(3))) unsigned int*)lds, 16, 0, 0);
}

// ---------------- router ----------------
__global__ __launch_bounds__(256) void router_kernel(
    const float* __restrict__ X, const float* __restrict__ GW,
    const float* __restrict__ SGW, int* __restrict__ cnt,
    int* __restrict__ tok_e, float* __restrict__ tok_w, float* __restrict__ sg)
{
  const int tkn = blockIdx.x, t = threadIdx.x;
  const float* xr = X + (size_t)tkn * HDIM;
  float a[NEXP + 1];
  #pragma unroll
  for (int e = 0; e <= NEXP; ++e) a[e] = 0.f;
  for (int h = t; h < HDIM; h += 256) {
    const float xv = xr[h];
    #pragma unroll
    for (int e = 0; e < NEXP; ++e) a[e] += xv * GW[e * HDIM + h];
    a[NEXP] += xv * SGW[h];
  }
  #pragma unroll
  for (int off = 32; off > 0; off >>= 1) {
    #pragma unroll
    for (int e = 0; e <= NEXP; ++e) a[e] += __shfl_down(a[e], off);
  }
  __shared__ float red[4][NEXP + 1];
  if ((t & 63) == 0) {
    #pragma unroll
    for (int e = 0; e <= NEXP; ++e) red[t >> 6][e] = a[e];
  }
  __syncthreads();
  if (t == 0) {
    float l[NEXP + 1];
    #pragma unroll
    for (int e = 0; e <= NEXP; ++e) l[e] = red[0][e] + red[1][e] + red[2][e] + red[3][e];
    int i1 = 0;
    #pragma unroll
    for (int e = 1; e < NEXP; ++e) if (l[e] > l[i1]) i1 = e;
    int i2 = (i1 == 0) ? 1 : 0;
    #pragma unroll
    for (int e = 0; e < NEXP; ++e) if (e != i1 && e != i2 && l[e] > l[i2]) i2 = e;
    const float w1 = 1.f / (1.f + __expf(l[i2] - l[i1]));   // softmax+top2+renorm == sigmoid(diff)
    tok_e[tkn * 2 + 0] = i1; tok_e[tkn * 2 + 1] = i2;
    tok_w[tkn * 2 + 0] = w1; tok_w[tkn * 2 + 1] = 1.f - w1;
    atomicAdd(&cnt[i1], 1); atomicAdd(&cnt[i2], 1);
    sg[tkn] = 1.f / (1.f + __expf(-l[NEXP]));
  }
}

__global__ void scan_kernel(const int* __restrict__ cnt, int* __restrict__ offs) {
  if (threadIdx.x == 0) {
    int r = 0;
    for (int e = 0; e < NEXP; ++e) { offs[e] = r; r += cnt[e]; }
  }
}

__global__ __launch_bounds__(256) void build_kernel(
    const int* __restrict__ tok_e, const float* __restrict__ tok_w,
    const int* __restrict__ offs, int* __restrict__ cur,
    int* __restrict__ list, float* __restrict__ wl)
{
  const int tkn = blockIdx.x * 256 + threadIdx.x;
  if (tkn >= TOK) return;
  #pragma unroll
  for (int k = 0; k < 2; ++k) {
    const int e = tok_e[tkn * 2 + k];
    const int pos = atomicAdd(&cur[e], 1);
    const int slot = offs[e] + pos;
    list[slot] = tkn;
    wl[slot] = tok_w[tkn * 2 + k];
  }
}

// ---------------- preprocessing ----------------
__global__ __launch_bounds__(256) void cvt_kernel(
    const float* __restrict__ src, unsigned short* __restrict__ dst, int n4)
{
  const int i = blockIdx.x * 512 + threadIdx.x;
  #pragma unroll
  for (int p = 0; p < 2; ++p) {
    const int j = i + p * 256;
    if (j < n4) {
      const float4 v = ((const float4*)src)[j];
      ushort4 b; b.x = f2b(v.x); b.y = f2b(v.y); b.z = f2b(v.z); b.w = f2b(v.w);
      ((ushort4*)dst)[j] = b;
    }
  }
}

// f32 [R][C] -> bf16 [C][R], per-z matrix. grid (C/64, R/64, nmat)
__global__ __launch_bounds__(256) void transpose_cvt_kernel(
    const float* __restrict__ src, unsigned short* __restrict__ dst,
    const int R, const int C)
{
  __shared__ unsigned short tile[64][72];
  const size_t mat = (size_t)blockIdx.z * R * C;
  const int c0 = blockIdx.x * 64, r0 = blockIdx.y * 64;
  const int t = threadIdx.x;
  const int rr = t >> 4, cc = (t & 15) * 4;
  #pragma unroll
  for (int p = 0; p < 4; ++p) {
    const int r = rr + p * 16;
    const float4 v = *(const float4*)(src + mat + (size_t)(r0 + r) * C + c0 + cc);
    tile[cc + 0][r] = f2b(v.x);
    tile[cc + 1][r] = f2b(v.y);
    tile[cc + 2][r] = f2b(v.z);
    tile[cc + 3][r] = f2b(v.w);
  }
  __syncthreads();
  #pragma unroll
  for (int p = 0; p < 2; ++p) {
    const int id = p * 256 + t;
    const int c = id >> 3, q = id & 7;
    const uint4 v = *(const uint4*)&tile[c][q * 8];
    *(uint4*)(dst + mat + (size_t)(c0 + c) * R + r0 + q * 8) = v;
  }
}

// ---------------- bf16 GEMM kernels (pre-transposed B: [N][K]) ----------------
// LDS granule layout (both operands): row m (128 rows), granule g (8 x 16B):
//   LDS[m*128 + g*16] holds source k-granule k8 = g ^ (m&7)   (XOR swizzle)
// global_load_lds: linear LDS dest (wave base + lane*16), pre-swizzled per-lane src.
// Fragment read: bf16x8 at m*128 + ((kk ^ (m&7)) << 4) -- 2-way max (free).

template<bool GATHER>
__global__ __launch_bounds__(256) void gateup_bf_kernel(
    const unsigned short* __restrict__ Xb,   // bf16 [TOK][HDIM]
    const unsigned short* __restrict__ WgT,  // bf16 [(E)][N][HDIM]
    const unsigned short* __restrict__ WuT,
    unsigned short* __restrict__ Cout,       // bf16 [rows][N]
    const int* __restrict__ list, const int* __restrict__ offs,
    const int* __restrict__ cnt, const int N, const int NT)
{
  __shared__ char smem[49152];
  char* sA  = smem;
  char* sBg = smem + 16384;
  char* sBu = smem + 32768;

  // bijective XCD swizzle (gridDim.x % 8 == 0), then mt-fastest decomposition:
  // all 16 M-tiles of one weight panel run contiguously on one XCD.
  int wg = blockIdx.x;
  wg = (wg & 7) * (gridDim.x >> 3) + (wg >> 3);
  const int mt = wg & 15;
  const int pn = wg >> 4;

  const int t = threadIdx.x;
  int rowbase, mcnt, n0;
  const unsigned short *Wg, *Wu;
  if (GATHER) {
    const int e = pn / NT, n = pn % NT;
    mcnt = cnt[e] - mt * 128;
    if (mcnt <= 0) return;
    rowbase = offs[e] + mt * 128;
    n0 = n * 128;
    Wg = WgT + (size_t)e * N * HDIM;
    Wu = WuT + (size_t)e * N * HDIM;
  } else {
    rowbase = mt * 128;           // MT=16 covers TOK
    mcnt = 128;
    n0 = pn * 128;
    Wg = WgT; Wu = WuT;
  }

  const int w = t >> 6, lane = t & 63;
  const int wr = w >> 1, wc = w & 1;
  const int lcol = lane & 15, lk = lane >> 4;

  f32x4 accg[4][4], accu[4][4];
  #pragma unroll
  for (int i = 0; i < 4; ++i)
    #pragma unroll
    for (int j = 0; j < 4; ++j) { accg[i][j] = {0.f,0.f,0.f,0.f}; accu[i][j] = {0.f,0.f,0.f,0.f}; }

  // per-lane source granules: s = p*256 + t; m = s>>3; k8 = (s&7)^(m&7)
  int arow[4], bm[4], koff[4];
  #pragma unroll
  for (int p = 0; p < 4; ++p) {
    const int s = p * 256 + t;
    const int m = s >> 3;
    bm[p] = m;
    koff[p] = ((s & 7) ^ (m & 7)) << 3;
    arow[p] = GATHER ? list[rowbase + m] : (rowbase + m);   // list zero-padded
  }

  const int KSTEPS = HDIM / 64;
  for (int kt = 0; kt < KSTEPS; ++kt) {
    const int k0 = kt * 64;
    if (kt) __syncthreads();
    #pragma unroll
    for (int p = 0; p < 4; ++p) {
      const int lb = (p * 256 + (t & 192)) * 16;   // wave-uniform LDS base
      async16(sA  + lb, Xb + (size_t)arow[p] * HDIM + k0 + koff[p]);
      async16(sBg + lb, Wg + (size_t)(n0 + bm[p]) * HDIM + k0 + koff[p]);
      async16(sBu + lb, Wu + (size_t)(n0 + bm[p]) * HDIM + k0 + koff[p]);
    }
    __syncthreads();   // drains vmcnt (gload_lds) + lgkm
    #pragma unroll
    for (int ks = 0; ks < 2; ++ks) {
      bf16x8 af[4], bg[4], bu[4];
      #pragma unroll
      for (int fm = 0; fm < 4; ++fm) {
        const int m = wr * 64 + fm * 16 + lcol;
        af[fm] = *(const bf16x8*)(sA + m * 128 + (((ks * 4 + lk) ^ (m & 7)) << 4));
      }
      #pragma unroll
      for (int fn = 0; fn < 4; ++fn) {
        const int n = wc * 64 + fn * 16 + lcol;
        const int ra = n * 128 + (((ks * 4 + lk) ^ (n & 7)) << 4);
        bg[fn] = *(const bf16x8*)(sBg + ra);
        bu[fn] = *(const bf16x8*)(sBu + ra);
      }
      #pragma unroll
      for (int fm = 0; fm < 4; ++fm)
        #pragma unroll
        for (int fn = 0; fn < 4; ++fn) {
          accg[fm][fn] = __builtin_amdgcn_mfma_f32_16x16x32_bf16(af[fm], bg[fn], accg[fm][fn], 0, 0, 0);
          accu[fm][fn] = __builtin_amdgcn_mfma_f32_16x16x32_bf16(af[fm], bu[fn], accu[fm][fn], 0, 0, 0);
        }
    }
  }
  #pragma unroll
  for (int fm = 0; fm < 4; ++fm) {
    #pragma unroll
    for (int fn = 0; fn < 4; ++fn) {
      const int col = n0 + wc * 64 + fn * 16 + lcol;
      #pragma unroll
      for (int r = 0; r < 4; ++r) {
        const int lrow = wr * 64 + fm * 16 + lk * 4 + r;
        if (lrow < mcnt) {
          const float gv = accg[fm][fn][r];
          const float uv = accu[fm][fn][r];
          const float hv = gv * uv / (1.f + __expf(-gv));
          Cout[(size_t)(rowbase + lrow) * N + col] = f2b(hv);
        }
      }
    }
  }
}

// down: out is a zeroed accumulator; both variants atomicAdd.
// EXPERT: += wl[slot]*v at row list[slot].  shared: += sg[row]*v (KSPLIT-way split-K).
template<bool EXPERT, int KSPLIT>
__global__ __launch_bounds__(256) void down_bf_kernel(
    const unsigned short* __restrict__ Abuf,  // bf16 [rows][K]
    const unsigned short* __restrict__ BT,    // bf16 [(E)][HDIM][K]
    float* __restrict__ out,
    const int* __restrict__ list, const float* __restrict__ wl,
    const int* __restrict__ offs, const int* __restrict__ cnt,
    const int K, const int ktps)
{
  __shared__ char smem[32768];
  char* sA = smem;
  char* sB = smem + 16384;

  int wg = blockIdx.x;
  wg = (wg & 7) * (gridDim.x >> 3) + (wg >> 3);
  const int ksp = wg % KSPLIT;
  const int mt  = (wg / KSPLIT) & 15;
  const int pn  = wg / (KSPLIT * 16);   // NT = HDIM/128 = 16 for both variants

  const int t = threadIdx.x;
  int rowbase, mcnt, n0;
  const unsigned short* Bm;
  if (EXPERT) {
    const int e = pn >> 4, n = pn & 15;
    mcnt = cnt[e] - mt * 128;
    if (mcnt <= 0) return;
    rowbase = offs[e] + mt * 128;
    n0 = n * 128;
    Bm = BT + (size_t)e * HDIM * K;
  } else {
    rowbase = mt * 128;
    mcnt = 128;
    n0 = pn * 128;
    Bm = BT;
  }
  const int w = t >> 6, lane = t & 63;
  const int wr = w >> 1, wc = w & 1;
  const int lcol = lane & 15, lk = lane >> 4;

  f32x4 acc[4][4];
  #pragma unroll
  for (int i = 0; i < 4; ++i)
    #pragma unroll
    for (int j = 0; j < 4; ++j) acc[i][j] = {0.f,0.f,0.f,0.f};

  int bm[4], koff[4];
  #pragma unroll
  for (int p = 0; p < 4; ++p) {
    const int s = p * 256 + t;
    const int m = s >> 3;
    bm[p] = m;
    koff[p] = ((s & 7) ^ (m & 7)) << 3;
  }

  const int kbeg = ksp * ktps, kend = kbeg + ktps;
  for (int kt = kbeg; kt < kend; ++kt) {
    const int k0 = kt * 64;
    if (kt != kbeg) __syncthreads();
    #pragma unroll
    for (int p = 0; p < 4; ++p) {
      const int lb = (p * 256 + (t & 192)) * 16;
      async16(sA + lb, Abuf + (size_t)(rowbase + bm[p]) * K + k0 + koff[p]);
      async16(sB + lb, Bm + (size_t)(n0 + bm[p]) * K + k0 + koff[p]);
    }
    __syncthreads();
    #pragma unroll
    for (int ks = 0; ks < 2; ++ks) {
      bf16x8 af[4], bfr[4];
      #pragma unroll
      for (int fm = 0; fm < 4; ++fm) {
        const int m = wr * 64 + fm * 16 + lcol;
        af[fm] = *(const bf16x8*)(sA + m * 128 + (((ks * 4 + lk) ^ (m & 7)) << 4));
      }
      #pragma unroll
      for (int fn = 0; fn < 4; ++fn) {
        const int n = wc * 64 + fn * 16 + lcol;
        bfr[fn] = *(const bf16x8*)(sB + n * 128 + (((ks * 4 + lk) ^ (n & 7)) << 4));
      }
      #pragma unroll
      for (int fm = 0; fm < 4; ++fm)
        #pragma unroll
        for (int fn = 0; fn < 4; ++fn)
          acc[fm][fn] = __builtin_amdgcn_mfma_f32_16x16x32_bf16(af[fm], bfr[fn], acc[fm][fn], 0, 0, 0);
    }
  }
  #pragma unroll
  for (int fm = 0; fm < 4; ++fm) {
    #pragma unroll
    for (int fn = 0; fn < 4; ++fn) {
      const int col = n0 + wc * 64 + fn * 16 + lcol;
      #pragma unroll
      for (int r = 0; r < 4; ++r) {
        const int lrow = wr * 64 + fm * 16 + lk * 4 + r;
        if (lrow < mcnt) {
          const float v = acc[fm][fn][r];
          if (EXPERT) {
            const int slot = rowbase + lrow;
            atomicAdd(out + (size_t)list[slot] * HDIM + col, wl[slot] * v);
          } else {
            const int row = rowbase + lrow;
            atomicAdd(out + (size_t)row * HDIM + col, wl[row] * v);
          }
        }
      }
    }
  }
}

// ================= legacy f32-weight path (fallback if ws too small) =================
template<bool GATHER>
__global__ __launch_bounds__(256) void gateup_kernel(
    const float* __restrict__ X,
    const float* __restrict__ WgA, const float* __restrict__ WuA,
    unsigned short* __restrict__ Cout,
    const int* __restrict__ list, const int* __restrict__ offs,
    const int* __restrict__ cnt, const int N)
{
  __shared__ char smem[49152];
  char* sA  = smem;
  char* sBg = smem + 16384;
  char* sBu = smem + 32768;
  const int t = threadIdx.x;
  const int nt = blockIdx.x;
  int rowbase, mcnt;
  const float *Wg, *Wu;
  if (GATHER) {
    const int e  = blockIdx.y >> 4;
    const int mt = blockIdx.y & 15;
    mcnt = cnt[e] - mt * 128;
    if (mcnt <= 0) return;
    rowbase = offs[e] + mt * 128;
    Wg = WgA + (size_t)e * HDIM * N;
    Wu = WuA + (size_t)e * HDIM * N;
  } else {
    rowbase = blockIdx.y * 128;
    mcnt = 128;
    Wg = WgA; Wu = WuA;
  }
  const int n0 = nt * 128;
  const int w = t >> 6, lane = t & 63;
  const int wr = w >> 1, wc = w & 1;
  const int lcol = lane & 15, lk = lane >> 4;
  f32x4 accg[4][4], accu[4][4];
  #pragma unroll
  for (int i = 0; i < 4; ++i)
    #pragma unroll
    for (int j = 0; j < 4; ++j) { accg[i][j] = {0.f,0.f,0.f,0.f}; accu[i][j] = {0.f,0.f,0.f,0.f}; }
  int arow[8];
  #pragma unroll
  for (int p = 0; p < 8; ++p) {
    const int m = p * 16 + (t >> 4);
    arow[p] = GATHER ? list[rowbase + m] : (rowbase + m);
  }
  const int ak4 = (t & 15) << 2;
  const int bn = t & 127, bkh = t >> 7;
  const int KSTEPS = HDIM / 64;
  for (int kt = 0; kt < KSTEPS; ++kt) {
    const int k0 = kt * 64;
    if (kt) __syncthreads();
    #pragma unroll
    for (int p = 0; p < 8; ++p) {
      const int m = p * 16 + (t >> 4);
      const float4 v = *(const float4*)(X + (size_t)arow[p] * HDIM + k0 + ak4);
      ushort4 b; b.x = f2b(v.x); b.y = f2b(v.y); b.z = f2b(v.z); b.w = f2b(v.w);
      *(ushort4*)(sA + m * 128 + ((((ak4 >> 3) ^ (m & 7)) << 4) | ((ak4 & 7) << 1))) = b;
    }
    #pragma unroll
    for (int p = 0; p < 8; ++p) {
      const int k4 = (p << 1) | bkh;
      const size_t gb = (size_t)(k0 + (k4 << 2)) * N + n0 + bn;
      const int wa = bn * 128 + ((((k4 >> 1) ^ (bn & 7)) << 4) | ((k4 & 1) << 3));
      ushort4 vg, vu;
      vg.x = f2b(Wg[gb]);                 vu.x = f2b(Wu[gb]);
      vg.y = f2b(Wg[gb + (size_t)N]);     vu.y = f2b(Wu[gb + (size_t)N]);
      vg.z = f2b(Wg[gb + 2*(size_t)N]);   vu.z = f2b(Wu[gb + 2*(size_t)N]);
      vg.w = f2b(Wg[gb + 3*(size_t)N]);   vu.w = f2b(Wu[gb + 3*(size_t)N]);
      *(ushort4*)(sBg + wa) = vg;
      *(ushort4*)(sBu + wa) = vu;
    }
    __syncthreads();
    #pragma unroll
    for (int ks = 0; ks < 2; ++ks) {
      bf16x8 af[4], bg[4], bu[4];
      #pragma unroll
      for (int fm = 0; fm < 4; ++fm) {
        const int m = wr * 64 + fm * 16 + lcol;
        af[fm] = *(const bf16x8*)(sA + m * 128 + (((ks * 4 + lk) ^ (m & 7)) << 4));
      }
      #pragma unroll
      for (int fn = 0; fn < 4; ++fn) {
        const int n = wc * 64 + fn * 16 + lcol;
        const int ra = n * 128 + (((ks * 4 + lk) ^ (n & 7)) << 4);
        bg[fn] = *(const bf16x8*)(sBg + ra);
        bu[fn] = *(const bf16x8*)(sBu + ra);
      }
      #pragma unroll
      for (int fm = 0; fm < 4; ++fm)
        #pragma unroll
        for (int fn = 0; fn < 4; ++fn) {
          accg[fm][fn] = __builtin_amdgcn_mfma_f32_16x16x32_bf16(af[fm], bg[fn], accg[fm][fn], 0, 0, 0);
          accu[fm][fn] = __builtin_amdgcn_mfma_f32_16x16x32_bf16(af[fm], bu[fn], accu[fm][fn], 0, 0, 0);
        }
    }
  }
  #pragma unroll
  for (int fm = 0; fm < 4; ++fm) {
    #pragma unroll
    for (int fn = 0; fn < 4; ++fn) {
      const int col = n0 + wc * 64 + fn * 16 + lcol;
      #pragma unroll
      for (int r = 0; r < 4; ++r) {
        const int lrow = wr * 64 + fm * 16 + lk * 4 + r;
        if (lrow < mcnt) {
          const float gv = accg[fm][fn][r];
          const float uv = accu[fm][fn][r];
          Cout[(size_t)(rowbase + lrow) * N + col] = f2b(gv * uv / (1.f + __expf(-gv)));
        }
      }
    }
  }
}

template<bool EXPERT>
__global__ __launch_bounds__(256) void down_kernel(
    const unsigned short* __restrict__ Abuf,
    const float* __restrict__ Ball,
    float* __restrict__ out,
    const int* __restrict__ list, const float* __restrict__ wl,
    const int* __restrict__ offs, const int* __restrict__ cnt, const int K)
{
  __shared__ char smem[32768];
  char* sA = smem;
  char* sB = smem + 16384;
  const int t = threadIdx.x;
  const int nt = blockIdx.x;
  int rowbase, mcnt;
  const float* Bm;
  if (EXPERT) {
    const int e  = blockIdx.y >> 4;
    const int mt = blockIdx.y & 15;
    mcnt = cnt[e] - mt * 128;
    if (mcnt <= 0) return;
    rowbase = offs[e] + mt * 128;
    Bm = Ball + (size_t)e * K * HDIM;
  } else {
    rowbase = blockIdx.y * 128;
    mcnt = 128;
    Bm = Ball;
  }
  const int n0 = nt * 128;
  const int w = t >> 6, lane = t & 63;
  const int wr = w >> 1, wc = w & 1;
  const int lcol = lane & 15, lk = lane >> 4;
  f32x4 acc[4][4];
  #pragma unroll
  for (int i = 0; i < 4; ++i)
    #pragma unroll
    for (int j = 0; j < 4; ++j) acc[i][j] = {0.f,0.f,0.f,0.f};
  const int bn = t & 127, bkh = t >> 7;
  const int KSTEPS = K / 64;
  for (int kt = 0; kt < KSTEPS; ++kt) {
    const int k0 = kt * 64;
    if (kt) __syncthreads();
    #pragma unroll
    for (int p = 0; p < 4; ++p) {
      const int s = p * 256 + t;
      const int m = s >> 3;
      const int k8 = (s & 7) ^ (m & 7);
      const uint4 v = *(const uint4*)(Abuf + (size_t)(rowbase + m) * K + k0 + (k8 << 3));
      *(uint4*)(sA + s * 16) = v;
    }
    #pragma unroll
    for (int p = 0; p < 8; ++p) {
      const int k4 = (p << 1) | bkh;
      const size_t gb = (size_t)(k0 + (k4 << 2)) * HDIM + n0 + bn;
      const int wa = bn * 128 + ((((k4 >> 1) ^ (bn & 7)) << 4) | ((k4 & 1) << 3));
      ushort4 vb;
      vb.x = f2b(Bm[gb]);
      vb.y = f2b(Bm[gb + HDIM]);
      vb.z = f2b(Bm[gb + 2 * HDIM]);
      vb.w = f2b(Bm[gb + 3 * HDIM]);
      *(ushort4*)(sB + wa) = vb;
    }
    __syncthreads();
    #pragma unroll
    for (int ks = 0; ks < 2; ++ks) {
      bf16x8 af[4], bfr[4];
      #pragma unroll
      for (int fm = 0; fm < 4; ++fm) {
        const int m = wr * 64 + fm * 16 + lcol;
        af[fm] = *(const bf16x8*)(sA + m * 128 + (((ks * 4 + lk) ^ (m & 7)) << 4));
      }
      #pragma unroll
      for (int fn = 0; fn < 4; ++fn) {
        const int n = wc * 64 + fn * 16 + lcol;
        bfr[fn] = *(const bf16x8*)(sB + n * 128 + (((ks * 4 + lk) ^ (n & 7)) << 4));
      }
      #pragma unroll
      for (int fm = 0; fm < 4; ++fm)
        #pragma unroll
        for (int fn = 0; fn < 4; ++fn)
          acc[fm][fn] = __builtin_amdgcn_mfma_f32_16x16x32_bf16(af[fm], bfr[fn], acc[fm][fn], 0, 0, 0);
    }
  }
  #pragma unroll
  for (int fm = 0; fm < 4; ++fm) {
    #pragma unroll
    for (int fn = 0; fn < 4; ++fn) {
      const int col = n0 + wc * 64 + fn * 16 + lcol;
      #pragma unroll
      for (int r = 0; r < 4; ++r) {
        const int lrow = wr * 64 + fm * 16 + lk * 4 + r;
        if (lrow < mcnt) {
          const float v = acc[fm][fn][r];
          if (EXPERT) {
            const int slot = rowbase + lrow;
            atomicAdd(out + (size_t)list[slot] * HDIM + col, wl[slot] * v);
          } else {
            const int row = rowbase + lrow;
            out[(size_t)row * HDIM + col] = wl[row] * v;
          }
        }
      }
    }
  }
}

extern "C" void kernel_launch(void* const* d_in, const int* in_sizes, int n_in,
                              void* d_out, int out_size, void* d_ws, size_t ws_size,
                              hipStream_t stream)
{
  const float* x       = (const float*)d_in[0];
  const float* gate_w  = (const float*)d_in[1];
  const float* w_gate  = (const float*)d_in[2];
  const float* w_up    = (const float*)d_in[3];
  const float* w_down  = (const float*)d_in[4];
  const float* sw_gate = (const float*)d_in[5];
  const float* sw_up   = (const float*)d_in[6];
  const float* sw_down = (const float*)d_in[7];
  const float* sgw     = (const float*)d_in[8];

  float* out = (float*)d_out;   // f32 [TOK][H]; pure accumulator (zeroed below)
  char* ws = (char*)d_ws;

  const size_t NEED = 136000000;

  if (ws_size >= NEED) {
    unsigned short* Xb   = (unsigned short*)ws;                     //  8,388,608
    unsigned short* R1a  = (unsigned short*)(ws + 8388608);         // 46,137,344
    unsigned short* R1b  = (unsigned short*)(ws + 54525952);        // 46,137,344
    unsigned short* shb  = (unsigned short*)(ws + 100663296);       // 23,068,672
    unsigned short* hb   = (unsigned short*)(ws + 123731968);       // 11,894,784
    char* meta = ws + 135626752;
    int*   cnt   = (int*)(meta);
    int*   cur   = (int*)(meta + 256);
    int*   offs  = (int*)(meta + 512);
    int*   list  = (int*)(meta + 768);
    float* wl    = (float*)(meta + 768 + 17152);
    int*   tok_e = (int*)(meta + 768 + 2 * 17152);
    float* tok_w = (float*)(meta + 768 + 2 * 17152 + 16384);
    float* sg    = (float*)(meta + 768 + 2 * 17152 + 32768);

    hipMemsetAsync(meta, 0, 768 + 2 * 17152, stream);
    hipMemsetAsync(out, 0, (size_t)TOK * HDIM * 4, stream);

    cvt_kernel<<<TOK * HDIM / 4 / 512, 256, 0, stream>>>(x, Xb, TOK * HDIM / 4);
    router_kernel<<<TOK, 256, 0, stream>>>(x, gate_w, sgw, cnt, tok_e, tok_w, sg);
    scan_kernel<<<1, 64, 0, stream>>>(cnt, offs);
    build_kernel<<<8, 256, 0, stream>>>(tok_e, tok_w, offs, cur, list, wl);

    // shared gateup: grid 44 panels x 16 mtiles = 704
    transpose_cvt_kernel<<<dim3(ISDIM / 64, HDIM / 64, 1), 256, 0, stream>>>(sw_gate, R1a, HDIM, ISDIM);
    transpose_cvt_kernel<<<dim3(ISDIM / 64, HDIM / 64, 1), 256, 0, stream>>>(sw_up,   R1b, HDIM, ISDIM);
    gateup_bf_kernel<false><<<704, 256, 0, stream>>>(
        Xb, R1a, R1b, shb, nullptr, nullptr, nullptr, ISDIM, 44);
    // shared down: 16 panels x 16 mtiles x 2 ksplit = 512
    transpose_cvt_kernel<<<dim3(HDIM / 64, ISDIM / 64, 1), 256, 0, stream>>>(sw_down, R1a, ISDIM, HDIM);
    down_bf_kernel<false, 2><<<512, 256, 0, stream>>>(
        shb, R1a, out, nullptr, sg, nullptr, nullptr, ISDIM, (ISDIM / 64) / 2);
    // expert gateup: (8e x 11n) panels x 16 mtiles = 1408
    transpose_cvt_kernel<<<dim3(IDIM / 64, HDIM / 64, NEXP), 256, 0, stream>>>(w_gate, R1a, HDIM, IDIM);
    transpose_cvt_kernel<<<dim3(IDIM / 64, HDIM / 64, NEXP), 256, 0, stream>>>(w_up,   R1b, HDIM, IDIM);
    gateup_bf_kernel<true><<<1408, 256, 0, stream>>>(
        Xb, R1a, R1b, hb, list, offs, cnt, IDIM, 11);
    // expert down: (8e x 16n) panels x 16 mtiles = 2048
    transpose_cvt_kernel<<<dim3(HDIM / 64, IDIM / 64, NEXP), 256, 0, stream>>>(w_down, R1a, IDIM, HDIM);
    down_bf_kernel<true, 1><<<2048, 256, 0, stream>>>(
        hb, R1a, out, list, wl, offs, cnt, IDIM, IDIM / 64);
  } else {
    // ---- legacy path ----
    unsigned short* sh_buf = (unsigned short*)ws;
    unsigned short* h_buf  = (unsigned short*)(ws + 23068672);
    char* meta = ws + 34963456;
    int*   cnt   = (int*)(meta);
    int*   cur   = (int*)(meta + 256);
    int*   offs  = (int*)(meta + 512);
    int*   list  = (int*)(meta + 768);
    float* wl    = (float*)(meta + 768 + 17152);
    int*   tok_e = (int*)(meta + 768 + 2 * 17152);
    float* tok_w = (float*)(meta + 768 + 2 * 17152 + 16384);
    float* sg    = (float*)(meta + 768 + 2 * 17152 + 32768);

    hipMemsetAsync(meta, 0, 768 + 2 * 17152, stream);
    router_kernel<<<TOK, 256, 0, stream>>>(x, gate_w, sgw, cnt, tok_e, tok_w, sg);
    scan_kernel<<<1, 64, 0, stream>>>(cnt, offs);
    build_kernel<<<8, 256, 0, stream>>>(tok_e, tok_w, offs, cur, list, wl);
    gateup_kernel<false><<<dim3(ISDIM / 128, TOK / 128), 256, 0, stream>>>(
        x, sw_gate, sw_up, sh_buf, nullptr, nullptr, nullptr, ISDIM);
    down_kernel<false><<<dim3(HDIM / 128, TOK / 128), 256, 0, stream>>>(
        sh_buf, sw_down, out, nullptr, sg, nullptr, nullptr, ISDIM);
    gateup_kernel<true><<<dim3(IDIM / 128, NEXP * 16), 256, 0, stream>>>(
        x, w_gate, w_up, h_buf, list, offs, cnt, IDIM);
    down_kernel<true><<<dim3(HDIM / 128, NEXP * 16), 256, 0, stream>>>(
        h_buf, w_down, out, list, wl, offs, cnt, IDIM);
  }
}

// Round 5
// 667.315 us; speedup vs baseline: 1.0114x; 1.0114x over previous
//
#include <hip/hip_runtime.h>
#include <hip/hip_bf16.h>
#include <stdint.h>

// Qwen3.5 MoE block: router top-2 sparse dispatch + shared expert (SwiGLU), bf16 MFMA.
// B=2,S=1024 -> TOK=2048 tokens. H=2048, I=1408, IS=5632, E=8, K=2. Output f32.
// Round 5: FUSED gateup (shared+expert) and FUSED down (shared splitK4 + expert)
// dispatches to fix the 1.4-blocks/CU latency exposure of the expert GEMMs.
// Block mapping mt-major/panel-minor (alive-fraction uniform mod 8 XCDs).
#define TOK   2048
#define HDIM  2048
#define IDIM  1408
#define ISDIM 5632
#define NEXP  8

typedef float  f32x4  __attribute__((ext_vector_type(4)));
typedef short  bf16x8 __attribute__((ext_vector_type(8)));

__device__ __forceinline__ unsigned short f2b(float f) {
  union { float f; uint32_t u; } v; v.f = f;
  return (unsigned short)((v.u + 0x7fffu + ((v.u >> 16) & 1u)) >> 16); // RNE
}

// async global->LDS DMA, 16 B per lane: LDS dest wave-uniform base + lane*16.
__device__ __forceinline__ void async16(void* lds, const void* g) {
  __builtin_amdgcn_global_load_lds(
      (const __attribute__((address_space(1))) unsigned int*)g,
      (__attribute__((address_space(3))) unsigned int*)lds, 16, 0, 0);
}

// ---------------- router ----------------
__global__ __launch_bounds__(256) void router_kernel(
    const float* __restrict__ X, const float* __restrict__ GW,
    const float* __restrict__ SGW, int* __restrict__ cnt,
    int* __restrict__ tok_e, float* __restrict__ tok_w, float* __restrict__ sg)
{
  const int tkn = blockIdx.x, t = threadIdx.x;
  const float* xr = X + (size_t)tkn * HDIM;
  float a[NEXP + 1];
  #pragma unroll
  for (int e = 0; e <= NEXP; ++e) a[e] = 0.f;
  for (int h = t; h < HDIM; h += 256) {
    const float xv = xr[h];
    #pragma unroll
    for (int e = 0; e < NEXP; ++e) a[e] += xv * GW[e * HDIM + h];
    a[NEXP] += xv * SGW[h];
  }
  #pragma unroll
  for (int off = 32; off > 0; off >>= 1) {
    #pragma unroll
    for (int e = 0; e <= NEXP; ++e) a[e] += __shfl_down(a[e], off);
  }
  __shared__ float red[4][NEXP + 1];
  if ((t & 63) == 0) {
    #pragma unroll
    for (int e = 0; e <= NEXP; ++e) red[t >> 6][e] = a[e];
  }
  __syncthreads();
  if (t == 0) {
    float l[NEXP + 1];
    #pragma unroll
    for (int e = 0; e <= NEXP; ++e) l[e] = red[0][e] + red[1][e] + red[2][e] + red[3][e];
    int i1 = 0;
    #pragma unroll
    for (int e = 1; e < NEXP; ++e) if (l[e] > l[i1]) i1 = e;
    int i2 = (i1 == 0) ? 1 : 0;
    #pragma unroll
    for (int e = 0; e < NEXP; ++e) if (e != i1 && e != i2 && l[e] > l[i2]) i2 = e;
    const float w1 = 1.f / (1.f + __expf(l[i2] - l[i1]));   // softmax+top2+renorm == sigmoid(diff)
    tok_e[tkn * 2 + 0] = i1; tok_e[tkn * 2 + 1] = i2;
    tok_w[tkn * 2 + 0] = w1; tok_w[tkn * 2 + 1] = 1.f - w1;
    atomicAdd(&cnt[i1], 1); atomicAdd(&cnt[i2], 1);
    sg[tkn] = 1.f / (1.f + __expf(-l[NEXP]));
  }
}

__global__ void scan_kernel(const int* __restrict__ cnt, int* __restrict__ offs) {
  if (threadIdx.x == 0) {
    int r = 0;
    for (int e = 0; e < NEXP; ++e) { offs[e] = r; r += cnt[e]; }
  }
}

__global__ __launch_bounds__(256) void build_kernel(
    const int* __restrict__ tok_e, const float* __restrict__ tok_w,
    const int* __restrict__ offs, int* __restrict__ cur,
    int* __restrict__ list, float* __restrict__ wl)
{
  const int tkn = blockIdx.x * 256 + threadIdx.x;
  if (tkn >= TOK) return;
  #pragma unroll
  for (int k = 0; k < 2; ++k) {
    const int e = tok_e[tkn * 2 + k];
    const int pos = atomicAdd(&cur[e], 1);
    const int slot = offs[e] + pos;
    list[slot] = tkn;
    wl[slot] = tok_w[tkn * 2 + k];
  }
}

// ---------------- preprocessing ----------------
__global__ __launch_bounds__(256) void cvt_kernel(
    const float* __restrict__ src, unsigned short* __restrict__ dst, int n4)
{
  const int i = blockIdx.x * 512 + threadIdx.x;
  #pragma unroll
  for (int p = 0; p < 2; ++p) {
    const int j = i + p * 256;
    if (j < n4) {
      const float4 v = ((const float4*)src)[j];
      ushort4 b; b.x = f2b(v.x); b.y = f2b(v.y); b.z = f2b(v.z); b.w = f2b(v.w);
      ((ushort4*)dst)[j] = b;
    }
  }
}

// f32 [R][C] -> bf16 [C][R], per-z matrix. grid (C/64, R/64, nmat)
__global__ __launch_bounds__(256) void transpose_cvt_kernel(
    const float* __restrict__ src, unsigned short* __restrict__ dst,
    const int R, const int C)
{
  __shared__ unsigned short tile[64][72];
  const size_t mat = (size_t)blockIdx.z * R * C;
  const int c0 = blockIdx.x * 64, r0 = blockIdx.y * 64;
  const int t = threadIdx.x;
  const int rr = t >> 4, cc = (t & 15) * 4;
  #pragma unroll
  for (int p = 0; p < 4; ++p) {
    const int r = rr + p * 16;
    const float4 v = *(const float4*)(src + mat + (size_t)(r0 + r) * C + c0 + cc);
    tile[cc + 0][r] = f2b(v.x);
    tile[cc + 1][r] = f2b(v.y);
    tile[cc + 2][r] = f2b(v.z);
    tile[cc + 3][r] = f2b(v.w);
  }
  __syncthreads();
  #pragma unroll
  for (int p = 0; p < 2; ++p) {
    const int id = p * 256 + t;
    const int c = id >> 3, q = id & 7;
    const uint4 v = *(const uint4*)&tile[c][q * 8];
    *(uint4*)(dst + mat + (size_t)(c0 + c) * R + r0 + q * 8) = v;
  }
}

// ---------------- FUSED gateup: shared (44 panels) + expert (88 panels) ----------------
// wg = mt*132 + pn, mt-major: alive fraction uniform across XCDs (pn-minor mod 8).
// LDS granule layout: row m (128), granule g: LDS[m*128+g*16] = src k8 = g^(m&7).
__global__ __launch_bounds__(256) void gateup_fused_kernel(
    const unsigned short* __restrict__ Xb,
    const unsigned short* __restrict__ Wshg, const unsigned short* __restrict__ Wshu,
    const unsigned short* __restrict__ Wexg, const unsigned short* __restrict__ Wexu,
    unsigned short* __restrict__ shb, unsigned short* __restrict__ hb,
    const int* __restrict__ list, const int* __restrict__ offs, const int* __restrict__ cnt)
{
  __shared__ char smem[49152];
  char* sA  = smem;
  char* sBg = smem + 16384;
  char* sBu = smem + 32768;

  const int wg = blockIdx.x;     // 0..2111
  const int mt = wg / 132;
  const int pn = wg % 132;
  const int t = threadIdx.x;

  int rowbase, mcnt, n0, N, gather;
  const unsigned short *Wg, *Wu;
  unsigned short* Cout;
  if (pn < 44) {
    N = ISDIM; n0 = pn * 128; rowbase = mt * 128; mcnt = 128; gather = 0;
    Wg = Wshg; Wu = Wshu; Cout = shb;
  } else {
    const int pnE = pn - 44;
    const int e = pnE / 11, n = pnE % 11;
    mcnt = cnt[e] - mt * 128;
    if (mcnt <= 0) return;
    N = IDIM; n0 = n * 128; rowbase = offs[e] + mt * 128; gather = 1;
    Wg = Wexg + (size_t)e * IDIM * HDIM;
    Wu = Wexu + (size_t)e * IDIM * HDIM;
    Cout = hb;
  }

  const int w = t >> 6, lane = t & 63;
  const int wr = w >> 1, wc = w & 1;
  const int lcol = lane & 15, lk = lane >> 4;

  f32x4 accg[4][4], accu[4][4];
  #pragma unroll
  for (int i = 0; i < 4; ++i)
    #pragma unroll
    for (int j = 0; j < 4; ++j) { accg[i][j] = {0.f,0.f,0.f,0.f}; accu[i][j] = {0.f,0.f,0.f,0.f}; }

  int arow[4], bm[4], koff[4];
  #pragma unroll
  for (int p = 0; p < 4; ++p) {
    const int s = p * 256 + t;
    const int m = s >> 3;
    bm[p] = m;
    koff[p] = ((s & 7) ^ (m & 7)) << 3;
    arow[p] = gather ? list[rowbase + m] : (rowbase + m);   // list zero-padded
  }

  const int KSTEPS = HDIM / 64;
  for (int kt = 0; kt < KSTEPS; ++kt) {
    const int k0 = kt * 64;
    if (kt) __syncthreads();
    #pragma unroll
    for (int p = 0; p < 4; ++p) {
      const int lb = (p * 256 + (t & 192)) * 16;   // wave-uniform LDS base
      async16(sA  + lb, Xb + (size_t)arow[p] * HDIM + k0 + koff[p]);
      async16(sBg + lb, Wg + (size_t)(n0 + bm[p]) * HDIM + k0 + koff[p]);
      async16(sBu + lb, Wu + (size_t)(n0 + bm[p]) * HDIM + k0 + koff[p]);
    }
    __syncthreads();   // drains vmcnt (gload_lds)
    #pragma unroll
    for (int ks = 0; ks < 2; ++ks) {
      bf16x8 af[4], bg[4], bu[4];
      #pragma unroll
      for (int fm = 0; fm < 4; ++fm) {
        const int m = wr * 64 + fm * 16 + lcol;
        af[fm] = *(const bf16x8*)(sA + m * 128 + (((ks * 4 + lk) ^ (m & 7)) << 4));
      }
      #pragma unroll
      for (int fn = 0; fn < 4; ++fn) {
        const int n = wc * 64 + fn * 16 + lcol;
        const int ra = n * 128 + (((ks * 4 + lk) ^ (n & 7)) << 4);
        bg[fn] = *(const bf16x8*)(sBg + ra);
        bu[fn] = *(const bf16x8*)(sBu + ra);
      }
      #pragma unroll
      for (int fm = 0; fm < 4; ++fm)
        #pragma unroll
        for (int fn = 0; fn < 4; ++fn) {
          accg[fm][fn] = __builtin_amdgcn_mfma_f32_16x16x32_bf16(af[fm], bg[fn], accg[fm][fn], 0, 0, 0);
          accu[fm][fn] = __builtin_amdgcn_mfma_f32_16x16x32_bf16(af[fm], bu[fn], accu[fm][fn], 0, 0, 0);
        }
    }
  }
  #pragma unroll
  for (int fm = 0; fm < 4; ++fm) {
    #pragma unroll
    for (int fn = 0; fn < 4; ++fn) {
      const int col = n0 + wc * 64 + fn * 16 + lcol;
      #pragma unroll
      for (int r = 0; r < 4; ++r) {
        const int lrow = wr * 64 + fm * 16 + lk * 4 + r;
        if (lrow < mcnt) {
          const float gv = accg[fm][fn][r];
          const float uv = accu[fm][fn][r];
          const float hv = gv * uv / (1.f + __expf(-gv));
          Cout[(size_t)(rowbase + lrow) * N + col] = f2b(hv);
        }
      }
    }
  }
}

// ---------------- FUSED down: shared splitK4 (1024 wg) + expert (2048 wg) ----------------
// Both 22 K-steps/block; all atomicAdd into zeroed out.
__global__ __launch_bounds__(256) void down_fused_kernel(
    const unsigned short* __restrict__ shb, const unsigned short* __restrict__ hb,
    const unsigned short* __restrict__ WdshT, const unsigned short* __restrict__ WdexT,
    float* __restrict__ out,
    const int* __restrict__ list, const float* __restrict__ wl, const float* __restrict__ sg,
    const int* __restrict__ offs, const int* __restrict__ cnt)
{
  __shared__ char smem[32768];
  char* sA = smem;
  char* sB = smem + 16384;

  const int wg = blockIdx.x;     // 0..3071
  const int t = threadIdx.x;
  int rowbase, mcnt, n0, K, kbeg, em;
  const unsigned short *Ap, *Bp;
  if (wg < 1024) {               // shared, splitK=4
    const int pn = wg & 15, layer = wg >> 4;     // layer = mt*4+ksp
    const int ksp = layer & 3, mt = layer >> 2;
    rowbase = mt * 128; mcnt = 128; n0 = pn * 128;
    K = ISDIM; kbeg = ksp * 22; em = 0;
    Ap = shb; Bp = WdshT;
  } else {                       // expert
    const int wgE = wg - 1024;
    const int pnE = wgE & 127, mt = wgE >> 7;
    const int e = pnE >> 4;
    mcnt = cnt[e] - mt * 128;
    if (mcnt <= 0) return;
    rowbase = offs[e] + mt * 128; n0 = (pnE & 15) * 128;
    K = IDIM; kbeg = 0; em = 1;
    Ap = hb; Bp = WdexT + (size_t)e * HDIM * IDIM;
  }

  const int w = t >> 6, lane = t & 63;
  const int wr = w >> 1, wc = w & 1;
  const int lcol = lane & 15, lk = lane >> 4;

  f32x4 acc[4][4];
  #pragma unroll
  for (int i = 0; i < 4; ++i)
    #pragma unroll
    for (int j = 0; j < 4; ++j) acc[i][j] = {0.f,0.f,0.f,0.f};

  int bm[4], koff[4];
  #pragma unroll
  for (int p = 0; p < 4; ++p) {
    const int s = p * 256 + t;
    const int m = s >> 3;
    bm[p] = m;
    koff[p] = ((s & 7) ^ (m & 7)) << 3;
  }

  for (int kt = kbeg; kt < kbeg + 22; ++kt) {
    const int k0 = kt * 64;
    if (kt != kbeg) __syncthreads();
    #pragma unroll
    for (int p = 0; p < 4; ++p) {
      const int lb = (p * 256 + (t & 192)) * 16;
      async16(sA + lb, Ap + (size_t)(rowbase + bm[p]) * K + k0 + koff[p]);
      async16(sB + lb, Bp + (size_t)(n0 + bm[p]) * K + k0 + koff[p]);
    }
    __syncthreads();
    #pragma unroll
    for (int ks = 0; ks < 2; ++ks) {
      bf16x8 af[4], bfr[4];
      #pragma unroll
      for (int fm = 0; fm < 4; ++fm) {
        const int m = wr * 64 + fm * 16 + lcol;
        af[fm] = *(const bf16x8*)(sA + m * 128 + (((ks * 4 + lk) ^ (m & 7)) << 4));
      }
      #pragma unroll
      for (int fn = 0; fn < 4; ++fn) {
        const int n = wc * 64 + fn * 16 + lcol;
        bfr[fn] = *(const bf16x8*)(sB + n * 128 + (((ks * 4 + lk) ^ (n & 7)) << 4));
      }
      #pragma unroll
      for (int fm = 0; fm < 4; ++fm)
        #pragma unroll
        for (int fn = 0; fn < 4; ++fn)
          acc[fm][fn] = __builtin_amdgcn_mfma_f32_16x16x32_bf16(af[fm], bfr[fn], acc[fm][fn], 0, 0, 0);
    }
  }
  #pragma unroll
  for (int fm = 0; fm < 4; ++fm) {
    #pragma unroll
    for (int fn = 0; fn < 4; ++fn) {
      const int col = n0 + wc * 64 + fn * 16 + lcol;
      #pragma unroll
      for (int r = 0; r < 4; ++r) {
        const int lrow = wr * 64 + fm * 16 + lk * 4 + r;
        if (lrow < mcnt) {
          const float v = acc[fm][fn][r];
          const int sl = rowbase + lrow;
          const int orow = em ? list[sl] : sl;
          const float sc = em ? wl[sl] : sg[sl];
          atomicAdd(out + (size_t)orow * HDIM + col, sc * v);
        }
      }
    }
  }
}

// ================= round-4 path (ws in [136MB, 182MB)) =================
template<bool GATHER>
__global__ __launch_bounds__(256) void gateup_bf_kernel(
    const unsigned short* __restrict__ Xb,
    const unsigned short* __restrict__ WgT, const unsigned short* __restrict__ WuT,
    unsigned short* __restrict__ Cout,
    const int* __restrict__ list, const int* __restrict__ offs,
    const int* __restrict__ cnt, const int N, const int NT)
{
  __shared__ char smem[49152];
  char* sA  = smem;
  char* sBg = smem + 16384;
  char* sBu = smem + 32768;
  int wg = blockIdx.x;
  wg = (wg & 7) * (gridDim.x >> 3) + (wg >> 3);
  const int mt = wg & 15;
  const int pn = wg >> 4;
  const int t = threadIdx.x;
  int rowbase, mcnt, n0;
  const unsigned short *Wg, *Wu;
  if (GATHER) {
    const int e = pn / NT, n = pn % NT;
    mcnt = cnt[e] - mt * 128;
    if (mcnt <= 0) return;
    rowbase = offs[e] + mt * 128;
    n0 = n * 128;
    Wg = WgT + (size_t)e * N * HDIM;
    Wu = WuT + (size_t)e * N * HDIM;
  } else {
    rowbase = mt * 128; mcnt = 128; n0 = pn * 128;
    Wg = WgT; Wu = WuT;
  }
  const int w = t >> 6, lane = t & 63;
  const int wr = w >> 1, wc = w & 1;
  const int lcol = lane & 15, lk = lane >> 4;
  f32x4 accg[4][4], accu[4][4];
  #pragma unroll
  for (int i = 0; i < 4; ++i)
    #pragma unroll
    for (int j = 0; j < 4; ++j) { accg[i][j] = {0.f,0.f,0.f,0.f}; accu[i][j] = {0.f,0.f,0.f,0.f}; }
  int arow[4], bm[4], koff[4];
  #pragma unroll
  for (int p = 0; p < 4; ++p) {
    const int s = p * 256 + t;
    const int m = s >> 3;
    bm[p] = m;
    koff[p] = ((s & 7) ^ (m & 7)) << 3;
    arow[p] = GATHER ? list[rowbase + m] : (rowbase + m);
  }
  const int KSTEPS = HDIM / 64;
  for (int kt = 0; kt < KSTEPS; ++kt) {
    const int k0 = kt * 64;
    if (kt) __syncthreads();
    #pragma unroll
    for (int p = 0; p < 4; ++p) {
      const int lb = (p * 256 + (t & 192)) * 16;
      async16(sA  + lb, Xb + (size_t)arow[p] * HDIM + k0 + koff[p]);
      async16(sBg + lb, Wg + (size_t)(n0 + bm[p]) * HDIM + k0 + koff[p]);
      async16(sBu + lb, Wu + (size_t)(n0 + bm[p]) * HDIM + k0 + koff[p]);
    }
    __syncthreads();
    #pragma unroll
    for (int ks = 0; ks < 2; ++ks) {
      bf16x8 af[4], bg[4], bu[4];
      #pragma unroll
      for (int fm = 0; fm < 4; ++fm) {
        const int m = wr * 64 + fm * 16 + lcol;
        af[fm] = *(const bf16x8*)(sA + m * 128 + (((ks * 4 + lk) ^ (m & 7)) << 4));
      }
      #pragma unroll
      for (int fn = 0; fn < 4; ++fn) {
        const int n = wc * 64 + fn * 16 + lcol;
        const int ra = n * 128 + (((ks * 4 + lk) ^ (n & 7)) << 4);
        bg[fn] = *(const bf16x8*)(sBg + ra);
        bu[fn] = *(const bf16x8*)(sBu + ra);
      }
      #pragma unroll
      for (int fm = 0; fm < 4; ++fm)
        #pragma unroll
        for (int fn = 0; fn < 4; ++fn) {
          accg[fm][fn] = __builtin_amdgcn_mfma_f32_16x16x32_bf16(af[fm], bg[fn], accg[fm][fn], 0, 0, 0);
          accu[fm][fn] = __builtin_amdgcn_mfma_f32_16x16x32_bf16(af[fm], bu[fn], accu[fm][fn], 0, 0, 0);
        }
    }
  }
  #pragma unroll
  for (int fm = 0; fm < 4; ++fm) {
    #pragma unroll
    for (int fn = 0; fn < 4; ++fn) {
      const int col = n0 + wc * 64 + fn * 16 + lcol;
      #pragma unroll
      for (int r = 0; r < 4; ++r) {
        const int lrow = wr * 64 + fm * 16 + lk * 4 + r;
        if (lrow < mcnt) {
          const float gv = accg[fm][fn][r];
          const float uv = accu[fm][fn][r];
          Cout[(size_t)(rowbase + lrow) * N + col] = f2b(gv * uv / (1.f + __expf(-gv)));
        }
      }
    }
  }
}

template<bool EXPERT, int KSPLIT>
__global__ __launch_bounds__(256) void down_bf_kernel(
    const unsigned short* __restrict__ Abuf,
    const unsigned short* __restrict__ BT,
    float* __restrict__ out,
    const int* __restrict__ list, const float* __restrict__ wl,
    const int* __restrict__ offs, const int* __restrict__ cnt,
    const int K, const int ktps)
{
  __shared__ char smem[32768];
  char* sA = smem;
  char* sB = smem + 16384;
  int wg = blockIdx.x;
  wg = (wg & 7) * (gridDim.x >> 3) + (wg >> 3);
  const int ksp = wg % KSPLIT;
  const int mt  = (wg / KSPLIT) & 15;
  const int pn  = wg / (KSPLIT * 16);
  const int t = threadIdx.x;
  int rowbase, mcnt, n0;
  const unsigned short* Bm;
  if (EXPERT) {
    const int e = pn >> 4, n = pn & 15;
    mcnt = cnt[e] - mt * 128;
    if (mcnt <= 0) return;
    rowbase = offs[e] + mt * 128;
    n0 = n * 128;
    Bm = BT + (size_t)e * HDIM * K;
  } else {
    rowbase = mt * 128; mcnt = 128; n0 = pn * 128;
    Bm = BT;
  }
  const int w = t >> 6, lane = t & 63;
  const int wr = w >> 1, wc = w & 1;
  const int lcol = lane & 15, lk = lane >> 4;
  f32x4 acc[4][4];
  #pragma unroll
  for (int i = 0; i < 4; ++i)
    #pragma unroll
    for (int j = 0; j < 4; ++j) acc[i][j] = {0.f,0.f,0.f,0.f};
  int bm[4], koff[4];
  #pragma unroll
  for (int p = 0; p < 4; ++p) {
    const int s = p * 256 + t;
    const int m = s >> 3;
    bm[p] = m;
    koff[p] = ((s & 7) ^ (m & 7)) << 3;
  }
  const int kbeg = ksp * ktps, kend = kbeg + ktps;
  for (int kt = kbeg; kt < kend; ++kt) {
    const int k0 = kt * 64;
    if (kt != kbeg) __syncthreads();
    #pragma unroll
    for (int p = 0; p < 4; ++p) {
      const int lb = (p * 256 + (t & 192)) * 16;
      async16(sA + lb, Abuf + (size_t)(rowbase + bm[p]) * K + k0 + koff[p]);
      async16(sB + lb, Bm + (size_t)(n0 + bm[p]) * K + k0 + koff[p]);
    }
    __syncthreads();
    #pragma unroll
    for (int ks = 0; ks < 2; ++ks) {
      bf16x8 af[4], bfr[4];
      #pragma unroll
      for (int fm = 0; fm < 4; ++fm) {
        const int m = wr * 64 + fm * 16 + lcol;
        af[fm] = *(const bf16x8*)(sA + m * 128 + (((ks * 4 + lk) ^ (m & 7)) << 4));
      }
      #pragma unroll
      for (int fn = 0; fn < 4; ++fn) {
        const int n = wc * 64 + fn * 16 + lcol;
        bfr[fn] = *(const bf16x8*)(sB + n * 128 + (((ks * 4 + lk) ^ (n & 7)) << 4));
      }
      #pragma unroll
      for (int fm = 0; fm < 4; ++fm)
        #pragma unroll
        for (int fn = 0; fn < 4; ++fn)
          acc[fm][fn] = __builtin_amdgcn_mfma_f32_16x16x32_bf16(af[fm], bfr[fn], acc[fm][fn], 0, 0, 0);
    }
  }
  #pragma unroll
  for (int fm = 0; fm < 4; ++fm) {
    #pragma unroll
    for (int fn = 0; fn < 4; ++fn) {
      const int col = n0 + wc * 64 + fn * 16 + lcol;
      #pragma unroll
      for (int r = 0; r < 4; ++r) {
        const int lrow = wr * 64 + fm * 16 + lk * 4 + r;
        if (lrow < mcnt) {
          const float v = acc[fm][fn][r];
          if (EXPERT) {
            const int slot = rowbase + lrow;
            atomicAdd(out + (size_t)list[slot] * HDIM + col, wl[slot] * v);
          } else {
            const int row = rowbase + lrow;
            atomicAdd(out + (size_t)row * HDIM + col, wl[row] * v);
          }
        }
      }
    }
  }
}

extern "C" void kernel_launch(void* const* d_in, const int* in_sizes, int n_in,
                              void* d_out, int out_size, void* d_ws, size_t ws_size,
                              hipStream_t stream)
{
  const float* x       = (const float*)d_in[0];
  const float* gate_w  = (const float*)d_in[1];
  const float* w_gate  = (const float*)d_in[2];
  const float* w_up    = (const float*)d_in[3];
  const float* w_down  = (const float*)d_in[4];
  const float* sw_gate = (const float*)d_in[5];
  const float* sw_up   = (const float*)d_in[6];
  const float* sw_down = (const float*)d_in[7];
  const float* sgw     = (const float*)d_in[8];

  float* out = (float*)d_out;   // f32 [TOK][H]; pure accumulator (zeroed)
  char* ws = (char*)d_ws;

  const size_t NEED_FUSED = 182000000;   // ~181.8 MB
  const size_t NEED_R4    = 136000000;

  if (ws_size >= NEED_FUSED) {
    // layout: all gate/up weights live simultaneously; down weights overlay W1/W3 later
    unsigned short* Xb  = (unsigned short*)ws;                      //   8,388,608
    unsigned short* W1  = (unsigned short*)(ws + 8388608);          //  23,068,672 shG^T / later shDown^T
    unsigned short* W2  = (unsigned short*)(ws + 31457280);         //  23,068,672 shU^T
    unsigned short* W3  = (unsigned short*)(ws + 54525952);         //  46,137,344 exG^T / later exDown^T
    unsigned short* W4  = (unsigned short*)(ws + 100663296);        //  46,137,344 exU^T
    unsigned short* shb = (unsigned short*)(ws + 146800640);        //  23,068,672
    unsigned short* hb  = (unsigned short*)(ws + 169869312);        //  11,894,784
    char* meta = ws + 181764096;
    int*   cnt   = (int*)(meta);
    int*   cur   = (int*)(meta + 256);
    int*   offs  = (int*)(meta + 512);
    int*   list  = (int*)(meta + 768);
    float* wl    = (float*)(meta + 768 + 17152);
    int*   tok_e = (int*)(meta + 768 + 2 * 17152);
    float* tok_w = (float*)(meta + 768 + 2 * 17152 + 16384);
    float* sg    = (float*)(meta + 768 + 2 * 17152 + 32768);

    hipMemsetAsync(meta, 0, 768 + 2 * 17152, stream);
    hipMemsetAsync(out, 0, (size_t)TOK * HDIM * 4, stream);

    cvt_kernel<<<TOK * HDIM / 4 / 512, 256, 0, stream>>>(x, Xb, TOK * HDIM / 4);
    router_kernel<<<TOK, 256, 0, stream>>>(x, gate_w, sgw, cnt, tok_e, tok_w, sg);
    scan_kernel<<<1, 64, 0, stream>>>(cnt, offs);
    build_kernel<<<8, 256, 0, stream>>>(tok_e, tok_w, offs, cur, list, wl);

    transpose_cvt_kernel<<<dim3(ISDIM / 64, HDIM / 64, 1), 256, 0, stream>>>(sw_gate, W1, HDIM, ISDIM);
    transpose_cvt_kernel<<<dim3(ISDIM / 64, HDIM / 64, 1), 256, 0, stream>>>(sw_up,   W2, HDIM, ISDIM);
    transpose_cvt_kernel<<<dim3(IDIM / 64, HDIM / 64, NEXP), 256, 0, stream>>>(w_gate, W3, HDIM, IDIM);
    transpose_cvt_kernel<<<dim3(IDIM / 64, HDIM / 64, NEXP), 256, 0, stream>>>(w_up,   W4, HDIM, IDIM);

    gateup_fused_kernel<<<2112, 256, 0, stream>>>(Xb, W1, W2, W3, W4, shb, hb, list, offs, cnt);

    transpose_cvt_kernel<<<dim3(HDIM / 64, ISDIM / 64, 1), 256, 0, stream>>>(sw_down, W1, ISDIM, HDIM);
    transpose_cvt_kernel<<<dim3(HDIM / 64, IDIM / 64, NEXP), 256, 0, stream>>>(w_down, W3, IDIM, HDIM);

    down_fused_kernel<<<3072, 256, 0, stream>>>(shb, hb, W1, W3, out, list, wl, sg, offs, cnt);
  } else if (ws_size >= NEED_R4) {
    unsigned short* Xb   = (unsigned short*)ws;
    unsigned short* R1a  = (unsigned short*)(ws + 8388608);
    unsigned short* R1b  = (unsigned short*)(ws + 54525952);
    unsigned short* shb  = (unsigned short*)(ws + 100663296);
    unsigned short* hb   = (unsigned short*)(ws + 123731968);
    char* meta = ws + 135626752;
    int*   cnt   = (int*)(meta);
    int*   cur   = (int*)(meta + 256);
    int*   offs  = (int*)(meta + 512);
    int*   list  = (int*)(meta + 768);
    float* wl    = (float*)(meta + 768 + 17152);
    int*   tok_e = (int*)(meta + 768 + 2 * 17152);
    float* tok_w = (float*)(meta + 768 + 2 * 17152 + 16384);
    float* sg    = (float*)(meta + 768 + 2 * 17152 + 32768);

    hipMemsetAsync(meta, 0, 768 + 2 * 17152, stream);
    hipMemsetAsync(out, 0, (size_t)TOK * HDIM * 4, stream);

    cvt_kernel<<<TOK * HDIM / 4 / 512, 256, 0, stream>>>(x, Xb, TOK * HDIM / 4);
    router_kernel<<<TOK, 256, 0, stream>>>(x, gate_w, sgw, cnt, tok_e, tok_w, sg);
    scan_kernel<<<1, 64, 0, stream>>>(cnt, offs);
    build_kernel<<<8, 256, 0, stream>>>(tok_e, tok_w, offs, cur, list, wl);

    transpose_cvt_kernel<<<dim3(ISDIM / 64, HDIM / 64, 1), 256, 0, stream>>>(sw_gate, R1a, HDIM, ISDIM);
    transpose_cvt_kernel<<<dim3(ISDIM / 64, HDIM / 64, 1), 256, 0, stream>>>(sw_up,   R1b, HDIM, ISDIM);
    gateup_bf_kernel<false><<<704, 256, 0, stream>>>(
        Xb, R1a, R1b, shb, nullptr, nullptr, nullptr, ISDIM, 44);
    transpose_cvt_kernel<<<dim3(HDIM / 64, ISDIM / 64, 1), 256, 0, stream>>>(sw_down, R1a, ISDIM, HDIM);
    down_bf_kernel<false, 2><<<512, 256, 0, stream>>>(
        shb, R1a, out, nullptr, sg, nullptr, nullptr, ISDIM, (ISDIM / 64) / 2);
    transpose_cvt_kernel<<<dim3(IDIM / 64, HDIM / 64, NEXP), 256, 0, stream>>>(w_gate, R1a, HDIM, IDIM);
    transpose_cvt_kernel<<<dim3(IDIM / 64, HDIM / 64, NEXP), 256, 0, stream>>>(w_up,   R1b, HDIM, IDIM);
    gateup_bf_kernel<true><<<1408, 256, 0, stream>>>(
        Xb, R1a, R1b, hb, list, offs, cnt, IDIM, 11);
    transpose_cvt_kernel<<<dim3(HDIM / 64, IDIM / 64, NEXP), 256, 0, stream>>>(w_down, R1a, IDIM, HDIM);
    down_bf_kernel<true, 1><<<2048, 256, 0, stream>>>(
        hb, R1a, out, list, wl, offs, cnt, IDIM, IDIM / 64);
  }
}

// Round 6
// 666.201 us; speedup vs baseline: 1.0130x; 1.0017x over previous
//
#include <hip/hip_runtime.h>
#include <hip/hip_bf16.h>
#include <stdint.h>

// Qwen3.5 MoE block: router top-2 sparse dispatch + shared expert (SwiGLU), bf16 MFMA.
// B=2,S=1024 -> TOK=2048 tokens. H=2048, I=1408, IS=5632, E=8, K=2. Output f32.
// Round 6: 2-phase prefetch double-buffered GEMMs (BK=32, one barrier/K-step,
// global_load_lds for tile t+1 issued before compute of tile t) + XCD-interleaved
// panel-contiguous block mapping (weight panel L2-resident per XCD).
#define TOK   2048
#define HDIM  2048
#define IDIM  1408
#define ISDIM 5632
#define NEXP  8

typedef float  f32x4  __attribute__((ext_vector_type(4)));
typedef short  bf16x8 __attribute__((ext_vector_type(8)));

__device__ __forceinline__ unsigned short f2b(float f) {
  union { float f; uint32_t u; } v; v.f = f;
  return (unsigned short)((v.u + 0x7fffu + ((v.u >> 16) & 1u)) >> 16); // RNE
}

// async global->LDS DMA, 16 B per lane: LDS dest wave-uniform base + lane*16.
__device__ __forceinline__ void async16(void* lds, const void* g) {
  __builtin_amdgcn_global_load_lds(
      (const __attribute__((address_space(1))) unsigned int*)g,
      (__attribute__((address_space(3))) unsigned int*)lds, 16, 0, 0);
}

// ---------------- router ----------------
__global__ __launch_bounds__(256) void router_kernel(
    const float* __restrict__ X, const float* __restrict__ GW,
    const float* __restrict__ SGW, int* __restrict__ cnt,
    int* __restrict__ tok_e, float* __restrict__ tok_w, float* __restrict__ sg)
{
  const int tkn = blockIdx.x, t = threadIdx.x;
  const float* xr = X + (size_t)tkn * HDIM;
  float a[NEXP + 1];
  #pragma unroll
  for (int e = 0; e <= NEXP; ++e) a[e] = 0.f;
  for (int h = t; h < HDIM; h += 256) {
    const float xv = xr[h];
    #pragma unroll
    for (int e = 0; e < NEXP; ++e) a[e] += xv * GW[e * HDIM + h];
    a[NEXP] += xv * SGW[h];
  }
  #pragma unroll
  for (int off = 32; off > 0; off >>= 1) {
    #pragma unroll
    for (int e = 0; e <= NEXP; ++e) a[e] += __shfl_down(a[e], off);
  }
  __shared__ float red[4][NEXP + 1];
  if ((t & 63) == 0) {
    #pragma unroll
    for (int e = 0; e <= NEXP; ++e) red[t >> 6][e] = a[e];
  }
  __syncthreads();
  if (t == 0) {
    float l[NEXP + 1];
    #pragma unroll
    for (int e = 0; e <= NEXP; ++e) l[e] = red[0][e] + red[1][e] + red[2][e] + red[3][e];
    int i1 = 0;
    #pragma unroll
    for (int e = 1; e < NEXP; ++e) if (l[e] > l[i1]) i1 = e;
    int i2 = (i1 == 0) ? 1 : 0;
    #pragma unroll
    for (int e = 0; e < NEXP; ++e) if (e != i1 && e != i2 && l[e] > l[i2]) i2 = e;
    const float w1 = 1.f / (1.f + __expf(l[i2] - l[i1]));   // softmax+top2+renorm == sigmoid(diff)
    tok_e[tkn * 2 + 0] = i1; tok_e[tkn * 2 + 1] = i2;
    tok_w[tkn * 2 + 0] = w1; tok_w[tkn * 2 + 1] = 1.f - w1;
    atomicAdd(&cnt[i1], 1); atomicAdd(&cnt[i2], 1);
    sg[tkn] = 1.f / (1.f + __expf(-l[NEXP]));
  }
}

__global__ void scan_kernel(const int* __restrict__ cnt, int* __restrict__ offs) {
  if (threadIdx.x == 0) {
    int r = 0;
    for (int e = 0; e < NEXP; ++e) { offs[e] = r; r += cnt[e]; }
  }
}

__global__ __launch_bounds__(256) void build_kernel(
    const int* __restrict__ tok_e, const float* __restrict__ tok_w,
    const int* __restrict__ offs, int* __restrict__ cur,
    int* __restrict__ list, float* __restrict__ wl)
{
  const int tkn = blockIdx.x * 256 + threadIdx.x;
  if (tkn >= TOK) return;
  #pragma unroll
  for (int k = 0; k < 2; ++k) {
    const int e = tok_e[tkn * 2 + k];
    const int pos = atomicAdd(&cur[e], 1);
    const int slot = offs[e] + pos;
    list[slot] = tkn;
    wl[slot] = tok_w[tkn * 2 + k];
  }
}

// ---------------- preprocessing ----------------
__global__ __launch_bounds__(256) void cvt_kernel(
    const float* __restrict__ src, unsigned short* __restrict__ dst, int n4)
{
  const int i = blockIdx.x * 512 + threadIdx.x;
  #pragma unroll
  for (int p = 0; p < 2; ++p) {
    const int j = i + p * 256;
    if (j < n4) {
      const float4 v = ((const float4*)src)[j];
      ushort4 b; b.x = f2b(v.x); b.y = f2b(v.y); b.z = f2b(v.z); b.w = f2b(v.w);
      ((ushort4*)dst)[j] = b;
    }
  }
}

// f32 [R][C] -> bf16 [C][R], per-z matrix. grid (C/64, R/64, nmat)
__global__ __launch_bounds__(256) void transpose_cvt_kernel(
    const float* __restrict__ src, unsigned short* __restrict__ dst,
    const int R, const int C)
{
  __shared__ unsigned short tile[64][72];
  const size_t mat = (size_t)blockIdx.z * R * C;
  const int c0 = blockIdx.x * 64, r0 = blockIdx.y * 64;
  const int t = threadIdx.x;
  const int rr = t >> 4, cc = (t & 15) * 4;
  #pragma unroll
  for (int p = 0; p < 4; ++p) {
    const int r = rr + p * 16;
    const float4 v = *(const float4*)(src + mat + (size_t)(r0 + r) * C + c0 + cc);
    tile[cc + 0][r] = f2b(v.x);
    tile[cc + 1][r] = f2b(v.y);
    tile[cc + 2][r] = f2b(v.z);
    tile[cc + 3][r] = f2b(v.w);
  }
  __syncthreads();
  #pragma unroll
  for (int p = 0; p < 2; ++p) {
    const int id = p * 256 + t;
    const int c = id >> 3, q = id & 7;
    const uint4 v = *(const uint4*)&tile[c][q * 8];
    *(uint4*)(dst + mat + (size_t)(c0 + c) * R + r0 + q * 8) = v;
  }
}

// ---------------- FUSED gateup, 2-phase dbuf, BK=32 ----------------
// LDS per buffer: A 8K + Bg 8K + Bu 8K = 24K; x2 buffers = 48K.
// Row m (128), k-granule g (4 x 16B): LDS[m*64+g*16] holds src granule g^((m>>1)&3).
// Read k-slice lk: addr m*64 + ((lk^((m>>1)&3))<<4)  -> <=2-way bank alias (free).
// Mapping: xcd=wg&7; column c = xcd + 8*(local>>4), mt = local&15 -> 16 mt-tiles of
// one weight panel run contiguously on one XCD (panel L2-resident).
__global__ __launch_bounds__(256) void gateup_fused_kernel(
    const unsigned short* __restrict__ Xb,
    const unsigned short* __restrict__ Wshg, const unsigned short* __restrict__ Wshu,
    const unsigned short* __restrict__ Wexg, const unsigned short* __restrict__ Wexu,
    unsigned short* __restrict__ shb, unsigned short* __restrict__ hb,
    const int* __restrict__ list, const int* __restrict__ offs, const int* __restrict__ cnt)
{
  __shared__ char smem[49152];

  const int xcd = blockIdx.x & 7;
  const int local = blockIdx.x >> 3;          // 0..271
  const int c = xcd + 8 * (local >> 4);       // column 0..135 (132 valid)
  const int mt = local & 15;
  if (c >= 132) return;
  const int t = threadIdx.x;

  int rowbase, mcnt, n0, N, gather;
  const unsigned short *Wg, *Wu;
  unsigned short* Cout;
  if (c < 44) {
    N = ISDIM; n0 = c * 128; rowbase = mt * 128; mcnt = 128; gather = 0;
    Wg = Wshg; Wu = Wshu; Cout = shb;
  } else {
    const int cE = c - 44;
    const int e = cE / 11, n = cE % 11;
    mcnt = cnt[e] - mt * 128;
    if (mcnt <= 0) return;
    N = IDIM; n0 = n * 128; rowbase = offs[e] + mt * 128; gather = 1;
    Wg = Wexg + (size_t)e * IDIM * HDIM;
    Wu = Wexu + (size_t)e * IDIM * HDIM;
    Cout = hb;
  }

  const int w = t >> 6, lane = t & 63;
  const int wr = w >> 1, wc = w & 1;
  const int lcol = lane & 15, lk = lane >> 4;

  f32x4 accg[4][4], accu[4][4];
  #pragma unroll
  for (int i = 0; i < 4; ++i)
    #pragma unroll
    for (int j = 0; j < 4; ++j) { accg[i][j] = {0.f,0.f,0.f,0.f}; accu[i][j] = {0.f,0.f,0.f,0.f}; }

  // staging source map: s = p*256+t; m = s>>2; g = s&3; src granule = g^((m>>1)&3)
  int arow[2], bm[2], koff[2];
  #pragma unroll
  for (int p = 0; p < 2; ++p) {
    const int s = p * 256 + t;
    const int m = s >> 2;
    bm[p] = m;
    koff[p] = (((s & 3) ^ ((m >> 1) & 3)) << 3);
    arow[p] = gather ? list[rowbase + m] : (rowbase + m);   // list zero-padded
  }

  auto STAGE = [&](int bb, int k0) {
    char* dA = smem + bb * 24576;
    #pragma unroll
    for (int p = 0; p < 2; ++p) {
      const int lb = (p * 256 + (t & 192)) * 16;
      async16(dA + lb,         Xb + (size_t)arow[p] * HDIM + k0 + koff[p]);
      async16(dA + 8192 + lb,  Wg + (size_t)(n0 + bm[p]) * HDIM + k0 + koff[p]);
      async16(dA + 16384 + lb, Wu + (size_t)(n0 + bm[p]) * HDIM + k0 + koff[p]);
    }
  };

  const int KST = HDIM / 32;   // 64
  STAGE(0, 0);
  __syncthreads();             // drains vmcnt for buf0

  for (int kt = 0; kt < KST; ++kt) {
    if (kt + 1 < KST) STAGE((kt + 1) & 1, (kt + 1) * 32);   // prefetch next tile
    const char* base = smem + (kt & 1) * 24576;
    bf16x8 af[4], bg[4], bu[4];
    #pragma unroll
    for (int fm = 0; fm < 4; ++fm) {
      const int m = wr * 64 + fm * 16 + lcol;
      af[fm] = *(const bf16x8*)(base + m * 64 + (((lk ^ ((m >> 1) & 3)) & 3) << 4));
    }
    #pragma unroll
    for (int fn = 0; fn < 4; ++fn) {
      const int n = wc * 64 + fn * 16 + lcol;
      const int ra = n * 64 + (((lk ^ ((n >> 1) & 3)) & 3) << 4);
      bg[fn] = *(const bf16x8*)(base + 8192 + ra);
      bu[fn] = *(const bf16x8*)(base + 16384 + ra);
    }
    #pragma unroll
    for (int fm = 0; fm < 4; ++fm)
      #pragma unroll
      for (int fn = 0; fn < 4; ++fn) {
        accg[fm][fn] = __builtin_amdgcn_mfma_f32_16x16x32_bf16(af[fm], bg[fn], accg[fm][fn], 0, 0, 0);
        accu[fm][fn] = __builtin_amdgcn_mfma_f32_16x16x32_bf16(af[fm], bu[fn], accu[fm][fn], 0, 0, 0);
      }
    __syncthreads();           // one barrier/K-step: drains next-tile vmcnt + syncs
  }

  #pragma unroll
  for (int fm = 0; fm < 4; ++fm) {
    #pragma unroll
    for (int fn = 0; fn < 4; ++fn) {
      const int col = n0 + wc * 64 + fn * 16 + lcol;
      #pragma unroll
      for (int r = 0; r < 4; ++r) {
        const int lrow = wr * 64 + fm * 16 + lk * 4 + r;
        if (lrow < mcnt) {
          const float gv = accg[fm][fn][r];
          const float uv = accu[fm][fn][r];
          const float hv = gv * uv / (1.f + __expf(-gv));
          Cout[(size_t)(rowbase + lrow) * N + col] = f2b(hv);
        }
      }
    }
  }
}

// ---------------- FUSED down, 2-phase dbuf, BK=32 ----------------
// columns: 64 shared (pn 0..15 x ksp 0..3, 44 steps each) + 128 expert (e x n, 44 steps).
// grid 3072 = 8 xcd x 24 columns x 16 mt. All atomicAdd into zeroed out.
__global__ __launch_bounds__(256) void down_fused_kernel(
    const unsigned short* __restrict__ shb, const unsigned short* __restrict__ hb,
    const unsigned short* __restrict__ WdshT, const unsigned short* __restrict__ WdexT,
    float* __restrict__ out,
    const int* __restrict__ list, const float* __restrict__ wl, const float* __restrict__ sg,
    const int* __restrict__ offs, const int* __restrict__ cnt)
{
  __shared__ char smem[32768];

  const int xcd = blockIdx.x & 7;
  const int local = blockIdx.x >> 3;          // 0..383
  const int c = xcd + 8 * (local >> 4);       // 0..191
  const int mt = local & 15;
  const int t = threadIdx.x;

  int rowbase, mcnt, n0, K, kbeg, em;
  const unsigned short *Ap, *Bp;
  if (c < 64) {                // shared, splitK=4
    const int pn = c & 15, ksp = c >> 4;
    rowbase = mt * 128; mcnt = 128; n0 = pn * 128;
    K = ISDIM; kbeg = ksp * 44; em = 0;
    Ap = shb; Bp = WdshT;
  } else {                     // expert
    const int cE = c - 64;
    const int e = cE >> 4, n = cE & 15;
    mcnt = cnt[e] - mt * 128;
    if (mcnt <= 0) return;
    rowbase = offs[e] + mt * 128; n0 = n * 128;
    K = IDIM; kbeg = 0; em = 1;
    Ap = hb; Bp = WdexT + (size_t)e * HDIM * IDIM;
  }

  const int w = t >> 6, lane = t & 63;
  const int wr = w >> 1, wc = w & 1;
  const int lcol = lane & 15, lk = lane >> 4;

  f32x4 acc[4][4];
  #pragma unroll
  for (int i = 0; i < 4; ++i)
    #pragma unroll
    for (int j = 0; j < 4; ++j) acc[i][j] = {0.f,0.f,0.f,0.f};

  int bm[2], koff[2];
  #pragma unroll
  for (int p = 0; p < 2; ++p) {
    const int s = p * 256 + t;
    const int m = s >> 2;
    bm[p] = m;
    koff[p] = (((s & 3) ^ ((m >> 1) & 3)) << 3);
  }

  auto STAGE = [&](int bb, int k0) {
    char* dA = smem + bb * 16384;
    #pragma unroll
    for (int p = 0; p < 2; ++p) {
      const int lb = (p * 256 + (t & 192)) * 16;
      async16(dA + lb,        Ap + (size_t)(rowbase + bm[p]) * K + k0 + koff[p]);
      async16(dA + 8192 + lb, Bp + (size_t)(n0 + bm[p]) * K + k0 + koff[p]);
    }
  };

  STAGE(0, kbeg * 32);
  __syncthreads();

  for (int j = 0; j < 44; ++j) {
    if (j + 1 < 44) STAGE((j + 1) & 1, (kbeg + j + 1) * 32);
    const char* base = smem + (j & 1) * 16384;
    bf16x8 af[4], bfr[4];
    #pragma unroll
    for (int fm = 0; fm < 4; ++fm) {
      const int m = wr * 64 + fm * 16 + lcol;
      af[fm] = *(const bf16x8*)(base + m * 64 + (((lk ^ ((m >> 1) & 3)) & 3) << 4));
    }
    #pragma unroll
    for (int fn = 0; fn < 4; ++fn) {
      const int n = wc * 64 + fn * 16 + lcol;
      bfr[fn] = *(const bf16x8*)(base + 8192 + n * 64 + (((lk ^ ((n >> 1) & 3)) & 3) << 4));
    }
    #pragma unroll
    for (int fm = 0; fm < 4; ++fm)
      #pragma unroll
      for (int fn = 0; fn < 4; ++fn)
        acc[fm][fn] = __builtin_amdgcn_mfma_f32_16x16x32_bf16(af[fm], bfr[fn], acc[fm][fn], 0, 0, 0);
    __syncthreads();
  }

  #pragma unroll
  for (int fm = 0; fm < 4; ++fm) {
    #pragma unroll
    for (int fn = 0; fn < 4; ++fn) {
      const int col = n0 + wc * 64 + fn * 16 + lcol;
      #pragma unroll
      for (int r = 0; r < 4; ++r) {
        const int lrow = wr * 64 + fm * 16 + lk * 4 + r;
        if (lrow < mcnt) {
          const float v = acc[fm][fn][r];
          const int sl = rowbase + lrow;
          const int orow = em ? list[sl] : sl;
          const float sc = em ? wl[sl] : sg[sl];
          atomicAdd(out + (size_t)orow * HDIM + col, sc * v);
        }
      }
    }
  }
}

// ================= round-4 path (ws in [136MB, 182MB)) =================
template<bool GATHER>
__global__ __launch_bounds__(256) void gateup_bf_kernel(
    const unsigned short* __restrict__ Xb,
    const unsigned short* __restrict__ WgT, const unsigned short* __restrict__ WuT,
    unsigned short* __restrict__ Cout,
    const int* __restrict__ list, const int* __restrict__ offs,
    const int* __restrict__ cnt, const int N, const int NT)
{
  __shared__ char smem[49152];
  char* sA  = smem;
  char* sBg = smem + 16384;
  char* sBu = smem + 32768;
  int wg = blockIdx.x;
  wg = (wg & 7) * (gridDim.x >> 3) + (wg >> 3);
  const int mt = wg & 15;
  const int pn = wg >> 4;
  const int t = threadIdx.x;
  int rowbase, mcnt, n0;
  const unsigned short *Wg, *Wu;
  if (GATHER) {
    const int e = pn / NT, n = pn % NT;
    mcnt = cnt[e] - mt * 128;
    if (mcnt <= 0) return;
    rowbase = offs[e] + mt * 128;
    n0 = n * 128;
    Wg = WgT + (size_t)e * N * HDIM;
    Wu = WuT + (size_t)e * N * HDIM;
  } else {
    rowbase = mt * 128; mcnt = 128; n0 = pn * 128;
    Wg = WgT; Wu = WuT;
  }
  const int w = t >> 6, lane = t & 63;
  const int wr = w >> 1, wc = w & 1;
  const int lcol = lane & 15, lk = lane >> 4;
  f32x4 accg[4][4], accu[4][4];
  #pragma unroll
  for (int i = 0; i < 4; ++i)
    #pragma unroll
    for (int j = 0; j < 4; ++j) { accg[i][j] = {0.f,0.f,0.f,0.f}; accu[i][j] = {0.f,0.f,0.f,0.f}; }
  int arow[4], bm[4], koff[4];
  #pragma unroll
  for (int p = 0; p < 4; ++p) {
    const int s = p * 256 + t;
    const int m = s >> 3;
    bm[p] = m;
    koff[p] = ((s & 7) ^ (m & 7)) << 3;
    arow[p] = GATHER ? list[rowbase + m] : (rowbase + m);
  }
  const int KSTEPS = HDIM / 64;
  for (int kt = 0; kt < KSTEPS; ++kt) {
    const int k0 = kt * 64;
    if (kt) __syncthreads();
    #pragma unroll
    for (int p = 0; p < 4; ++p) {
      const int lb = (p * 256 + (t & 192)) * 16;
      async16(sA  + lb, Xb + (size_t)arow[p] * HDIM + k0 + koff[p]);
      async16(sBg + lb, Wg + (size_t)(n0 + bm[p]) * HDIM + k0 + koff[p]);
      async16(sBu + lb, Wu + (size_t)(n0 + bm[p]) * HDIM + k0 + koff[p]);
    }
    __syncthreads();
    #pragma unroll
    for (int ks = 0; ks < 2; ++ks) {
      bf16x8 af[4], bg[4], bu[4];
      #pragma unroll
      for (int fm = 0; fm < 4; ++fm) {
        const int m = wr * 64 + fm * 16 + lcol;
        af[fm] = *(const bf16x8*)(sA + m * 128 + (((ks * 4 + lk) ^ (m & 7)) << 4));
      }
      #pragma unroll
      for (int fn = 0; fn < 4; ++fn) {
        const int n = wc * 64 + fn * 16 + lcol;
        const int ra = n * 128 + (((ks * 4 + lk) ^ (n & 7)) << 4);
        bg[fn] = *(const bf16x8*)(sBg + ra);
        bu[fn] = *(const bf16x8*)(sBu + ra);
      }
      #pragma unroll
      for (int fm = 0; fm < 4; ++fm)
        #pragma unroll
        for (int fn = 0; fn < 4; ++fn) {
          accg[fm][fn] = __builtin_amdgcn_mfma_f32_16x16x32_bf16(af[fm], bg[fn], accg[fm][fn], 0, 0, 0);
          accu[fm][fn] = __builtin_amdgcn_mfma_f32_16x16x32_bf16(af[fm], bu[fn], accu[fm][fn], 0, 0, 0);
        }
    }
  }
  #pragma unroll
  for (int fm = 0; fm < 4; ++fm) {
    #pragma unroll
    for (int fn = 0; fn < 4; ++fn) {
      const int col = n0 + wc * 64 + fn * 16 + lcol;
      #pragma unroll
      for (int r = 0; r < 4; ++r) {
        const int lrow = wr * 64 + fm * 16 + lk * 4 + r;
        if (lrow < mcnt) {
          const float gv = accg[fm][fn][r];
          const float uv = accu[fm][fn][r];
          Cout[(size_t)(rowbase + lrow) * N + col] = f2b(gv * uv / (1.f + __expf(-gv)));
        }
      }
    }
  }
}

template<bool EXPERT, int KSPLIT>
__global__ __launch_bounds__(256) void down_bf_kernel(
    const unsigned short* __restrict__ Abuf,
    const unsigned short* __restrict__ BT,
    float* __restrict__ out,
    const int* __restrict__ list, const float* __restrict__ wl,
    const int* __restrict__ offs, const int* __restrict__ cnt,
    const int K, const int ktps)
{
  __shared__ char smem[32768];
  char* sA = smem;
  char* sB = smem + 16384;
  int wg = blockIdx.x;
  wg = (wg & 7) * (gridDim.x >> 3) + (wg >> 3);
  const int ksp = wg % KSPLIT;
  const int mt  = (wg / KSPLIT) & 15;
  const int pn  = wg / (KSPLIT * 16);
  const int t = threadIdx.x;
  int rowbase, mcnt, n0;
  const unsigned short* Bm;
  if (EXPERT) {
    const int e = pn >> 4, n = pn & 15;
    mcnt = cnt[e] - mt * 128;
    if (mcnt <= 0) return;
    rowbase = offs[e] + mt * 128;
    n0 = n * 128;
    Bm = BT + (size_t)e * HDIM * K;
  } else {
    rowbase = mt * 128; mcnt = 128; n0 = pn * 128;
    Bm = BT;
  }
  const int w = t >> 6, lane = t & 63;
  const int wr = w >> 1, wc = w & 1;
  const int lcol = lane & 15, lk = lane >> 4;
  f32x4 acc[4][4];
  #pragma unroll
  for (int i = 0; i < 4; ++i)
    #pragma unroll
    for (int j = 0; j < 4; ++j) acc[i][j] = {0.f,0.f,0.f,0.f};
  int bm[4], koff[4];
  #pragma unroll
  for (int p = 0; p < 4; ++p) {
    const int s = p * 256 + t;
    const int m = s >> 3;
    bm[p] = m;
    koff[p] = ((s & 7) ^ (m & 7)) << 3;
  }
  const int kbeg = ksp * ktps, kend = kbeg + ktps;
  for (int kt = kbeg; kt < kend; ++kt) {
    const int k0 = kt * 64;
    if (kt != kbeg) __syncthreads();
    #pragma unroll
    for (int p = 0; p < 4; ++p) {
      const int lb = (p * 256 + (t & 192)) * 16;
      async16(sA + lb, Abuf + (size_t)(rowbase + bm[p]) * K + k0 + koff[p]);
      async16(sB + lb, Bm + (size_t)(n0 + bm[p]) * K + k0 + koff[p]);
    }
    __syncthreads();
    #pragma unroll
    for (int ks = 0; ks < 2; ++ks) {
      bf16x8 af[4], bfr[4];
      #pragma unroll
      for (int fm = 0; fm < 4; ++fm) {
        const int m = wr * 64 + fm * 16 + lcol;
        af[fm] = *(const bf16x8*)(sA + m * 128 + (((ks * 4 + lk) ^ (m & 7)) << 4));
      }
      #pragma unroll
      for (int fn = 0; fn < 4; ++fn) {
        const int n = wc * 64 + fn * 16 + lcol;
        bfr[fn] = *(const bf16x8*)(sB + n * 128 + (((ks * 4 + lk) ^ (n & 7)) << 4));
      }
      #pragma unroll
      for (int fm = 0; fm < 4; ++fm)
        #pragma unroll
        for (int fn = 0; fn < 4; ++fn)
          acc[fm][fn] = __builtin_amdgcn_mfma_f32_16x16x32_bf16(af[fm], bfr[fn], acc[fm][fn], 0, 0, 0);
    }
  }
  #pragma unroll
  for (int fm = 0; fm < 4; ++fm) {
    #pragma unroll
    for (int fn = 0; fn < 4; ++fn) {
      const int col = n0 + wc * 64 + fn * 16 + lcol;
      #pragma unroll
      for (int r = 0; r < 4; ++r) {
        const int lrow = wr * 64 + fm * 16 + lk * 4 + r;
        if (lrow < mcnt) {
          const float v = acc[fm][fn][r];
          if (EXPERT) {
            const int slot = rowbase + lrow;
            atomicAdd(out + (size_t)list[slot] * HDIM + col, wl[slot] * v);
          } else {
            const int row = rowbase + lrow;
            atomicAdd(out + (size_t)row * HDIM + col, wl[row] * v);
          }
        }
      }
    }
  }
}

extern "C" void kernel_launch(void* const* d_in, const int* in_sizes, int n_in,
                              void* d_out, int out_size, void* d_ws, size_t ws_size,
                              hipStream_t stream)
{
  const float* x       = (const float*)d_in[0];
  const float* gate_w  = (const float*)d_in[1];
  const float* w_gate  = (const float*)d_in[2];
  const float* w_up    = (const float*)d_in[3];
  const float* w_down  = (const float*)d_in[4];
  const float* sw_gate = (const float*)d_in[5];
  const float* sw_up   = (const float*)d_in[6];
  const float* sw_down = (const float*)d_in[7];
  const float* sgw     = (const float*)d_in[8];

  float* out = (float*)d_out;   // f32 [TOK][H]; pure accumulator (zeroed)
  char* ws = (char*)d_ws;

  const size_t NEED_FUSED = 182000000;   // ~181.8 MB
  const size_t NEED_R4    = 136000000;

  if (ws_size >= NEED_FUSED) {
    unsigned short* Xb  = (unsigned short*)ws;                      //   8,388,608
    unsigned short* W1  = (unsigned short*)(ws + 8388608);          //  23,068,672 shG^T / later shDown^T
    unsigned short* W2  = (unsigned short*)(ws + 31457280);         //  23,068,672 shU^T
    unsigned short* W3  = (unsigned short*)(ws + 54525952);         //  46,137,344 exG^T / later exDown^T
    unsigned short* W4  = (unsigned short*)(ws + 100663296);        //  46,137,344 exU^T
    unsigned short* shb = (unsigned short*)(ws + 146800640);        //  23,068,672
    unsigned short* hb  = (unsigned short*)(ws + 169869312);        //  11,894,784
    char* meta = ws + 181764096;
    int*   cnt   = (int*)(meta);
    int*   cur   = (int*)(meta + 256);
    int*   offs  = (int*)(meta + 512);
    int*   list  = (int*)(meta + 768);
    float* wl    = (float*)(meta + 768 + 17152);
    int*   tok_e = (int*)(meta + 768 + 2 * 17152);
    float* tok_w = (float*)(meta + 768 + 2 * 17152 + 16384);
    float* sg    = (float*)(meta + 768 + 2 * 17152 + 32768);

    hipMemsetAsync(meta, 0, 768 + 2 * 17152, stream);
    hipMemsetAsync(out, 0, (size_t)TOK * HDIM * 4, stream);

    cvt_kernel<<<TOK * HDIM / 4 / 512, 256, 0, stream>>>(x, Xb, TOK * HDIM / 4);
    router_kernel<<<TOK, 256, 0, stream>>>(x, gate_w, sgw, cnt, tok_e, tok_w, sg);
    scan_kernel<<<1, 64, 0, stream>>>(cnt, offs);
    build_kernel<<<8, 256, 0, stream>>>(tok_e, tok_w, offs, cur, list, wl);

    transpose_cvt_kernel<<<dim3(ISDIM / 64, HDIM / 64, 1), 256, 0, stream>>>(sw_gate, W1, HDIM, ISDIM);
    transpose_cvt_kernel<<<dim3(ISDIM / 64, HDIM / 64, 1), 256, 0, stream>>>(sw_up,   W2, HDIM, ISDIM);
    transpose_cvt_kernel<<<dim3(IDIM / 64, HDIM / 64, NEXP), 256, 0, stream>>>(w_gate, W3, HDIM, IDIM);
    transpose_cvt_kernel<<<dim3(IDIM / 64, HDIM / 64, NEXP), 256, 0, stream>>>(w_up,   W4, HDIM, IDIM);

    // grid 2176 = 8 xcd x 17 col-slots x 16 mt (cols >=132 return)
    gateup_fused_kernel<<<2176, 256, 0, stream>>>(Xb, W1, W2, W3, W4, shb, hb, list, offs, cnt);

    transpose_cvt_kernel<<<dim3(HDIM / 64, ISDIM / 64, 1), 256, 0, stream>>>(sw_down, W1, ISDIM, HDIM);
    transpose_cvt_kernel<<<dim3(HDIM / 64, IDIM / 64, NEXP), 256, 0, stream>>>(w_down, W3, IDIM, HDIM);

    // grid 3072 = 8 xcd x 24 columns x 16 mt
    down_fused_kernel<<<3072, 256, 0, stream>>>(shb, hb, W1, W3, out, list, wl, sg, offs, cnt);
  } else if (ws_size >= NEED_R4) {
    unsigned short* Xb   = (unsigned short*)ws;
    unsigned short* R1a  = (unsigned short*)(ws + 8388608);
    unsigned short* R1b  = (unsigned short*)(ws + 54525952);
    unsigned short* shb  = (unsigned short*)(ws + 100663296);
    unsigned short* hb   = (unsigned short*)(ws + 123731968);
    char* meta = ws + 135626752;
    int*   cnt   = (int*)(meta);
    int*   cur   = (int*)(meta + 256);
    int*   offs  = (int*)(meta + 512);
    int*   list  = (int*)(meta + 768);
    float* wl    = (float*)(meta + 768 + 17152);
    int*   tok_e = (int*)(meta + 768 + 2 * 17152);
    float* tok_w = (float*)(meta + 768 + 2 * 17152 + 16384);
    float* sg    = (float*)(meta + 768 + 2 * 17152 + 32768);

    hipMemsetAsync(meta, 0, 768 + 2 * 17152, stream);
    hipMemsetAsync(out, 0, (size_t)TOK * HDIM * 4, stream);

    cvt_kernel<<<TOK * HDIM / 4 / 512, 256, 0, stream>>>(x, Xb, TOK * HDIM / 4);
    router_kernel<<<TOK, 256, 0, stream>>>(x, gate_w, sgw, cnt, tok_e, tok_w, sg);
    scan_kernel<<<1, 64, 0, stream>>>(cnt, offs);
    build_kernel<<<8, 256, 0, stream>>>(tok_e, tok_w, offs, cur, list, wl);

    transpose_cvt_kernel<<<dim3(ISDIM / 64, HDIM / 64, 1), 256, 0, stream>>>(sw_gate, R1a, HDIM, ISDIM);
    transpose_cvt_kernel<<<dim3(ISDIM / 64, HDIM / 64, 1), 256, 0, stream>>>(sw_up,   R1b, HDIM, ISDIM);
    gateup_bf_kernel<false><<<704, 256, 0, stream>>>(
        Xb, R1a, R1b, shb, nullptr, nullptr, nullptr, ISDIM, 44);
    transpose_cvt_kernel<<<dim3(HDIM / 64, ISDIM / 64, 1), 256, 0, stream>>>(sw_down, R1a, ISDIM, HDIM);
    down_bf_kernel<false, 2><<<512, 256, 0, stream>>>(
        shb, R1a, out, nullptr, sg, nullptr, nullptr, ISDIM, (ISDIM / 64) / 2);
    transpose_cvt_kernel<<<dim3(IDIM / 64, HDIM / 64, NEXP), 256, 0, stream>>>(w_gate, R1a, HDIM, IDIM);
    transpose_cvt_kernel<<<dim3(IDIM / 64, HDIM / 64, NEXP), 256, 0, stream>>>(w_up,   R1b, HDIM, IDIM);
    gateup_bf_kernel<true><<<1408, 256, 0, stream>>>(
        Xb, R1a, R1b, hb, list, offs, cnt, IDIM, 11);
    transpose_cvt_kernel<<<dim3(HDIM / 64, IDIM / 64, NEXP), 256, 0, stream>>>(w_down, R1a, IDIM, HDIM);
    down_bf_kernel<true, 1><<<2048, 256, 0, stream>>>(
        hb, R1a, out, list, wl, offs, cnt, IDIM, IDIM / 64);
  }
}